// Round 2
// baseline (17577.312 us; speedup 1.0000x reference)
//
#include <hip/hip_runtime.h>
#include <math.h>

// ---- problem constants ----
#define BB    2048
#define DD    32
#define SS    32
#define HIST_ 50
#define ADIM_ 60
#define NHEAD_ 4
#define DH_   128
#define NL_   3
#define DM_   512
#define DFF_  1024
#define OUT_  256
#define FDIM_ 98
#define GDIM_ 561
#define CDIM_ 8384
#define MTOK  65536          // B*S
#define NCHUNK 4
#define MC    (MTOK/NCHUNK)  // 16384 rows per chunk
#define BC    (BB/NCHUNK)    // 512 batch per chunk

// =====================================================================
// Generic f32 GEMM:  C[m,n] = sum_k A[m*lda+k] * W[n*K+k]  (+bias, epilogues)
// 64x64 tile, BK=16, 256 threads, 4x4 micro-tile per thread.
// =====================================================================
template<bool RELU, bool RESID, bool ADDPOS, bool PROJSCAT>
__global__ __launch_bounds__(256) void gemm_nt(
    const float* __restrict__ A, int lda,
    const float* __restrict__ W,
    const float* __restrict__ bias,
    const float* __restrict__ resid,
    const float* __restrict__ pos,
    float* __restrict__ C, int ldc,
    int M, int N, int K)
{
    __shared__ __align__(16) float As[16][68];
    __shared__ __align__(16) float Ws[16][68];
    const int t  = threadIdx.x;
    const int tx = t & 15, ty = t >> 4;
    const int m0 = blockIdx.x * 64, n0 = blockIdx.y * 64;
    const int kk0  = t & 15;     // k-local for staging
    const int rowb = t >> 4;     // row-local base for staging
    float acc[4][4] = {};
    for (int k0 = 0; k0 < K; k0 += 16) {
#pragma unroll
        for (int i = 0; i < 4; ++i) {
            int r  = rowb + 16 * i;
            int gk = k0 + kk0;
            int gm = m0 + r;
            As[kk0][r] = (gm < M && gk < K) ? A[(size_t)gm * lda + gk] : 0.f;
            int gn = n0 + r;
            Ws[kk0][r] = (gn < N && gk < K) ? W[(size_t)gn * K + gk] : 0.f;
        }
        __syncthreads();
#pragma unroll
        for (int kk = 0; kk < 16; ++kk) {
            float4 a4 = *(const float4*)(&As[kk][ty * 4]);
            float4 b4 = *(const float4*)(&Ws[kk][tx * 4]);
            float av[4] = {a4.x, a4.y, a4.z, a4.w};
            float bv[4] = {b4.x, b4.y, b4.z, b4.w};
#pragma unroll
            for (int i = 0; i < 4; ++i)
#pragma unroll
                for (int j = 0; j < 4; ++j)
                    acc[i][j] = fmaf(av[i], bv[j], acc[i][j]);
        }
        __syncthreads();
    }
#pragma unroll
    for (int i = 0; i < 4; ++i) {
        int m = m0 + ty * 4 + i;
        if (m >= M) continue;
#pragma unroll
        for (int j = 0; j < 4; ++j) {
            int n = n0 + tx * 4 + j;
            if (n >= N) continue;
            float v = acc[i][j] + bias[n];
            if constexpr (ADDPOS) v += pos[(m & 31) * N + n];
            size_t oidx;
            if constexpr (PROJSCAT)
                oidx = (size_t)(m >> 5) * CDIM_ + (size_t)(m & 31) * OUT_ + n;
            else
                oidx = (size_t)m * ldc + n;
            if constexpr (RESID) v += resid[oidx];
            if constexpr (RELU) v = fmaxf(v, 0.f);
            C[oidx] = v;
        }
    }
}

// =====================================================================
// Features: Gram-Schmidt, mu, norms, vf, cos-pairs, f64 LU det, gf
// one 64-thread block per batch item
// =====================================================================
__global__ __launch_bounds__(64) void feat_kernel(
    const float* __restrict__ basis, float* __restrict__ vf, float* __restrict__ gf)
{
    const int b = blockIdx.x;
    const int t = threadIdx.x;
    __shared__ float bs[32][33], gsm[32][33], muls[32][32];
    __shared__ float gn2[32], bn_[32], gn_[32];
    __shared__ double lu[32][33];
    __shared__ int piv;
    __shared__ double detv;

    const float* bb = basis + (size_t)b * 1024;
    for (int r = 0; r < 16; ++r) {
        int idx = r * 64 + t;            // 0..1023
        bs[idx >> 5][idx & 31] = bb[idx];
    }
    __syncthreads();
    if (t < 32) {
        float s = 0.f;
        for (int d = 0; d < 32; ++d) s = fmaf(bs[t][d], bs[t][d], s);
        bn_[t] = sqrtf(s);
    }
    __syncthreads();

    // ---- classical Gram-Schmidt ----
    for (int j = 0; j < 32; ++j) {
        if (t < 32) {
            float m = 0.f;
            if (t < j) {
                float dot = 0.f;
                for (int d = 0; d < 32; ++d) dot = fmaf(gsm[t][d], bs[j][d], dot);
                float sq = gn2[t];
                m = dot / (sq > 0.f ? sq : 1.f);
            }
            muls[j][t] = m;
        }
        __syncthreads();
        float val = 0.f;
        if (t < 32) {
            float acc = bs[j][t];
            for (int k = 0; k < j; ++k) acc = fmaf(-muls[j][k], gsm[k][t], acc);
            gsm[j][t] = acc;
            val = acc * acc;
        }
#pragma unroll
        for (int off = 1; off < 32; off <<= 1) val += __shfl_xor(val, off, 64);
        if (t == 0) { gn2[j] = val; gn_[j] = sqrtf(val); }
        __syncthreads();
    }

    // ---- f64 LU with partial pivoting for det ----
    for (int r = 0; r < 16; ++r) {
        int idx = r * 64 + t;
        lu[idx >> 5][idx & 31] = (double)bs[idx >> 5][idx & 31];
    }
    if (t == 0) detv = 1.0;
    __syncthreads();
    for (int k = 0; k < 32; ++k) {
        if (t == 0) {
            int p = k; double best = fabs(lu[k][k]);
            for (int i = k + 1; i < 32; ++i) {
                double a = fabs(lu[i][k]);
                if (a > best) { best = a; p = i; }
            }
            piv = p;
            if (p != k) detv = -detv;
        }
        __syncthreads();
        int p = piv;
        if (p != k && t < 32) {
            double tmp = lu[k][t]; lu[k][t] = lu[p][t]; lu[p][t] = tmp;
        }
        __syncthreads();
        if (t == 0) detv *= lu[k][k];
        double pkk = lu[k][k];
        for (int i = k + 1 + (t >> 5); i < 32; i += 2) {
            double f = (pkk != 0.0) ? (lu[i][k] / pkk) : 0.0;
            int c = t & 31;
            if (c > k) lu[i][c] -= f * lu[k][c];
        }
        __syncthreads();
    }

    // ---- write vf: [basis(32), gs(32), bn, gn, mu(32)] = 98 per row ----
    for (int r = 0; r < 49; ++r) {
        int idx = r * 64 + t;            // 0..3135
        int i = idx / 98, c = idx % 98;
        float v;
        if (c < 32) v = bs[i][c];
        else if (c < 64) v = gsm[i][c - 32];
        else if (c == 64) v = bn_[i];
        else if (c == 65) v = gn_[i];
        else v = muls[i][c - 66];
        vf[(size_t)(b * 32 + i) * FDIM_ + c] = v;
    }

    // ---- gf: [odef, cos_upper(496), bn(32), gn(32)] ----
    float* gfb = gf + (size_t)b * GDIM_;
    for (int r = 0; r < 16; ++r) {
        int p = r * 64 + t;              // 0..1023
        int i = p >> 5, j = p & 31;
        if (i < j) {
            float dot = 0.f;
            for (int d = 0; d < 32; ++d) dot = fmaf(bs[i][d], bs[j][d], dot);
            float c = dot / ((bn_[i] + 1e-10f) * (bn_[j] + 1e-10f));
            int L = i * 31 - (i * (i - 1)) / 2 + (j - i - 1);
            gfb[1 + L] = c;
        }
    }
    if (t < 32) {
        gfb[497 + t] = bn_[t];
        gfb[529 + t] = gn_[t];
    }
    if (t == 0) {
        double pb = 1.0;
        for (int i = 0; i < 32; ++i) pb *= (double)bn_[i];
        double det = fabs(detv);
        gfb[0] = (float)(pb / (det + 1e-10));
    }
}

// =====================================================================
// Attention (one block per (batch,head)); in-place: O overwrites Q slice
// =====================================================================
__global__ __launch_bounds__(256) void attn_kernel(float* __restrict__ qkv)
{
    const int b = blockIdx.x >> 2, h = blockIdx.x & 3;
    __shared__ float qs[32][129], ks[32][129], vs_[32][129], ps[32][33];
    float* base = qkv + (size_t)b * 32 * 1536 + h * 128;
    const int t = threadIdx.x;
    for (int r = 0; r < 16; ++r) {
        int idx = r * 256 + t;           // 0..4095
        int s = idx >> 7, d = idx & 127;
        qs[s][d]  = base[(size_t)s * 1536 + d];
        ks[s][d]  = base[(size_t)s * 1536 + 512 + d];
        vs_[s][d] = base[(size_t)s * 1536 + 1024 + d];
    }
    __syncthreads();
    const float scale = 0.08838834764831845f;  // 1/sqrt(128)
#pragma unroll
    for (int r = 0; r < 4; ++r) {
        int p = r * 256 + t;             // 0..1023
        int i = p >> 5, j = p & 31;
        float acc = 0.f;
#pragma unroll
        for (int d = 0; d < 128; ++d) acc = fmaf(qs[i][d], ks[j][d], acc);
        ps[i][j] = acc * scale;
    }
    __syncthreads();
    if (t < 32) {
        float mx = -1e30f;
        for (int j = 0; j < 32; ++j) mx = fmaxf(mx, ps[t][j]);
        float sum = 0.f;
        for (int j = 0; j < 32; ++j) { float e = expf(ps[t][j] - mx); ps[t][j] = e; sum += e; }
        float inv = 1.f / sum;
        for (int j = 0; j < 32; ++j) ps[t][j] *= inv;
    }
    __syncthreads();
    for (int r = 0; r < 16; ++r) {
        int idx = r * 256 + t;
        int s = idx >> 7, d = idx & 127;
        float acc = 0.f;
#pragma unroll
        for (int j = 0; j < 32; ++j) acc = fmaf(ps[s][j], vs_[j][d], acc);
        base[(size_t)s * 1536 + d] = acc;
    }
}

// =====================================================================
// LayerNorm over 512 (in place), 4 rows per 256-thread block
// =====================================================================
__global__ __launch_bounds__(256) void ln_kernel(
    float* __restrict__ X, const float* __restrict__ g, const float* __restrict__ b)
{
    const int row  = blockIdx.x * 4 + (threadIdx.x >> 6);
    const int lane = threadIdx.x & 63;
    float* xr = X + (size_t)row * 512;
    float v[8];
    float s = 0.f;
#pragma unroll
    for (int i = 0; i < 8; ++i) { v[i] = xr[lane + 64 * i]; s += v[i]; }
#pragma unroll
    for (int off = 32; off; off >>= 1) s += __shfl_xor(s, off, 64);
    float mean = s * (1.f / 512.f);
    float vs = 0.f;
#pragma unroll
    for (int i = 0; i < 8; ++i) { float d = v[i] - mean; vs += d * d; }
#pragma unroll
    for (int off = 32; off; off >>= 1) vs += __shfl_xor(vs, off, 64);
    float inv = rsqrtf(vs * (1.f / 512.f) + 1e-5f);
#pragma unroll
    for (int i = 0; i < 8; ++i) {
        int c = lane + 64 * i;
        xr[c] = (v[i] - mean) * inv * g[c] + b[c];
    }
}

// =====================================================================
// Action-history gather: ae_in[b,pos,:] = act_emb[ah[b,pos]]
// =====================================================================
__global__ __launch_bounds__(256) void gather_kernel(
    const int* __restrict__ hist, const float* __restrict__ act_emb, float* __restrict__ out)
{
    int idx = blockIdx.x * 256 + threadIdx.x;    // B*HIST*32
    if (idx >= BB * HIST_ * 32) return;
    int d = idx & 31, e = idx >> 5;
    int a = hist[e];
    if (a == -1) a = ADIM_;
    out[idx] = act_emb[a * 32 + d];
}

// probs softmax over 60, one 64-lane block per row (in place on d_out)
__global__ __launch_bounds__(64) void softmax_kernel(float* __restrict__ logits)
{
    const int row = blockIdx.x;
    const int t = threadIdx.x;
    float v = (t < 60) ? logits[row * 60 + t] : -1e30f;
    float mx = v;
#pragma unroll
    for (int off = 32; off; off >>= 1) mx = fmaxf(mx, __shfl_xor(mx, off, 64));
    float e = (t < 60) ? expf(v - mx) : 0.f;
    float s = e;
#pragma unroll
    for (int off = 32; off; off >>= 1) s += __shfl_xor(s, off, 64);
    if (t < 60) logits[row * 60 + t] = e / s;
}

// value = h2b @ c3_W[0] + c3_b[0]; 4 rows per block
__global__ __launch_bounds__(256) void value_kernel(
    const float* __restrict__ h, const float* __restrict__ w,
    const float* __restrict__ bias, float* __restrict__ out)
{
    const int row  = blockIdx.x * 4 + (threadIdx.x >> 6);
    const int lane = threadIdx.x & 63;
    float s = 0.f;
#pragma unroll
    for (int i = 0; i < 8; ++i)
        s = fmaf(h[(size_t)row * 512 + lane + 64 * i], w[lane + 64 * i], s);
#pragma unroll
    for (int off = 32; off; off >>= 1) s += __shfl_xor(s, off, 64);
    if (lane == 0) out[row] = s + bias[0];
}

// =====================================================================
extern "C" void kernel_launch(void* const* d_in, const int* in_sizes, int n_in,
                              void* d_out, int out_size, void* d_ws, size_t ws_size,
                              hipStream_t stream)
{
    const float* basis  = (const float*)d_in[0];
    const int*   hist   = (const int*)  d_in[1];
    const float* emb_W  = (const float*)d_in[2];
    const float* emb_b  = (const float*)d_in[3];
    const float* pos    = (const float*)d_in[4];
    const float* qkv_W  = (const float*)d_in[5];
    const float* qkv_b  = (const float*)d_in[6];
    const float* out_W  = (const float*)d_in[7];
    const float* out_b  = (const float*)d_in[8];
    const float* ln1_g  = (const float*)d_in[9];
    const float* ln1_b  = (const float*)d_in[10];
    const float* ln2_g  = (const float*)d_in[11];
    const float* ln2_b  = (const float*)d_in[12];
    const float* ff1_W  = (const float*)d_in[13];
    const float* ff1_b  = (const float*)d_in[14];
    const float* ff2_W  = (const float*)d_in[15];
    const float* ff2_b  = (const float*)d_in[16];
    const float* proj_W = (const float*)d_in[17];
    const float* proj_b = (const float*)d_in[18];
    const float* g1_W   = (const float*)d_in[19];
    const float* g1_b   = (const float*)d_in[20];
    const float* g2_W   = (const float*)d_in[21];
    const float* g2_b   = (const float*)d_in[22];
    const float* act_emb= (const float*)d_in[23];
    const float* act1_W = (const float*)d_in[24];
    const float* act1_b = (const float*)d_in[25];
    const float* act2_W = (const float*)d_in[26];
    const float* act2_b = (const float*)d_in[27];
    const float* a1_W   = (const float*)d_in[28];
    const float* a1_b   = (const float*)d_in[29];
    const float* a2_W   = (const float*)d_in[30];
    const float* a2_b   = (const float*)d_in[31];
    const float* a3_W   = (const float*)d_in[32];
    const float* a3_b   = (const float*)d_in[33];
    const float* c1_W   = (const float*)d_in[34];
    const float* c1_b   = (const float*)d_in[35];
    const float* c2_W   = (const float*)d_in[36];
    const float* c2_b   = (const float*)d_in[37];
    const float* c3_W   = (const float*)d_in[38];
    const float* c3_b   = (const float*)d_in[39];

    // ---- workspace layout (floats), aliased by lifetime, ~260 MB ----
    // X    : [0, 33.5M)            alive stages 2-4; AEIN aliases it at stage 6
    // Abuf : [33.5M, 58.7M)        alive stages 1-3 (VF early); COMB aliases from stage 4
    // tail : GF, GE1, AE1, H1, H1B, H2, H2B
    float* ws   = (float*)d_ws;
    float* X    = ws;                           // 65536*512   = 33,554,432
    float* Abuf = X    + 33554432;              // 16384*1536  = 25,165,824
    float* VF   = Abuf;                         // 65536*98 = 6,422,528 (dead after embed)
    float* COMB = Abuf;                         // 2048*8384 = 17,170,432 (from stage 4)
    float* AEIN = X;                            // 2048*1600 (X dead after proj)
    float* GF   = Abuf + 25165824;              // 2048*561    = 1,148,928
    float* GE1  = GF   + 1148928;               // 2048*256
    float* AE1  = GE1  + 524288;                // 2048*128
    float* H1   = AE1  + 262144;                // 2048*512
    float* H1B  = H1   + 1048576;
    float* H2   = H1B  + 1048576;
    float* H2B  = H2   + 1048576;

    const dim3 blk(256);

    // 1) features (GS + mu + norms + cos + LU det)
    feat_kernel<<<BB, 64, 0, stream>>>(basis, VF, GF);

    // 2) embed: X = vf @ emb_W.T + emb_b + pos
    {
        dim3 g(MTOK / 64, DM_ / 64);
        gemm_nt<false,false,true,false><<<g, blk, 0, stream>>>(
            VF, FDIM_, emb_W, emb_b, nullptr, pos, X, DM_, MTOK, DM_, FDIM_);
    }

    // 3) transformer layers (batch-chunked x4 to cap workspace)
    for (int l = 0; l < NL_; ++l) {
        const float* qW = qkv_W + (size_t)l * 1536 * 512;
        const float* qB = qkv_b + l * 1536;
        const float* oW = out_W + (size_t)l * 512 * 512;
        const float* oB = out_b + l * 512;
        for (int c = 0; c < NCHUNK; ++c) {
            float* Xc = X + (size_t)c * MC * DM_;
            dim3 g1(MC / 64, 1536 / 64);
            gemm_nt<false,false,false,false><<<g1, blk, 0, stream>>>(
                Xc, DM_, qW, qB, nullptr, nullptr, Abuf, 1536, MC, 1536, DM_);
            attn_kernel<<<BC * NHEAD_, 256, 0, stream>>>(Abuf);
            dim3 g2(MC / 64, DM_ / 64);
            gemm_nt<false,true,false,false><<<g2, blk, 0, stream>>>(
                Abuf, 1536, oW, oB, Xc, nullptr, Xc, DM_, MC, DM_, DM_);
        }
        ln_kernel<<<MTOK / 4, 256, 0, stream>>>(X, ln1_g + l * 512, ln1_b + l * 512);

        const float* f1W = ff1_W + (size_t)l * 1024 * 512;
        const float* f1B = ff1_b + l * 1024;
        const float* f2W = ff2_W + (size_t)l * 512 * 1024;
        const float* f2B = ff2_b + l * 512;
        for (int c = 0; c < NCHUNK; ++c) {
            float* Xc = X + (size_t)c * MC * DM_;
            dim3 g1(MC / 64, DFF_ / 64);
            gemm_nt<true,false,false,false><<<g1, blk, 0, stream>>>(
                Xc, DM_, f1W, f1B, nullptr, nullptr, Abuf, DFF_, MC, DFF_, DM_);
            dim3 g2(MC / 64, DM_ / 64);
            gemm_nt<false,true,false,false><<<g2, blk, 0, stream>>>(
                Abuf, DFF_, f2W, f2B, Xc, nullptr, Xc, DM_, MC, DM_, DFF_);
        }
        ln_kernel<<<MTOK / 4, 256, 0, stream>>>(X, ln2_g + l * 512, ln2_b + l * 512);
    }

    // 4) proj -> COMB[:, :8192] (scatter); after this X is dead, Abuf becomes COMB
    {
        dim3 g(MTOK / 64, OUT_ / 64);
        gemm_nt<false,false,false,true><<<g, blk, 0, stream>>>(
            X, DM_, proj_W, proj_b, nullptr, nullptr, COMB, 0, MTOK, OUT_, DM_);
    }
    // 5) global-features MLP -> COMB[:, 8192:8320]
    {
        dim3 g(BB / 64, 256 / 64);
        gemm_nt<true,false,false,false><<<g, blk, 0, stream>>>(
            GF, GDIM_, g1_W, g1_b, nullptr, nullptr, GE1, 256, BB, 256, GDIM_);
        dim3 g2(BB / 64, 2);
        gemm_nt<false,false,false,false><<<g2, blk, 0, stream>>>(
            GE1, 256, g2_W, g2_b, nullptr, nullptr, COMB + 8192, CDIM_, BB, 128, 256);
    }
    // 6) action-history MLP -> COMB[:, 8320:8384]   (AEIN aliases dead X)
    gather_kernel<<<(BB * HIST_ * 32 + 255) / 256, 256, 0, stream>>>(hist, act_emb, AEIN);
    {
        dim3 g(BB / 64, 2);
        gemm_nt<true,false,false,false><<<g, blk, 0, stream>>>(
            AEIN, 1600, act1_W, act1_b, nullptr, nullptr, AE1, 128, BB, 128, 1600);
        dim3 g2(BB / 64, 1);
        gemm_nt<false,false,false,false><<<g2, blk, 0, stream>>>(
            AE1, 128, act2_W, act2_b, nullptr, nullptr, COMB + 8320, CDIM_, BB, 64, 128);
    }

    float* probs = (float*)d_out;
    float* value = probs + (size_t)BB * ADIM_;

    // 7) actor head
    {
        dim3 g(BB / 64, DM_ / 64);
        gemm_nt<true,false,false,false><<<g, blk, 0, stream>>>(
            COMB, CDIM_, a1_W, a1_b, nullptr, nullptr, H1, DM_, BB, DM_, CDIM_);
        gemm_nt<true,false,false,false><<<g, blk, 0, stream>>>(
            H1, DM_, a2_W, a2_b, nullptr, nullptr, H1B, DM_, BB, DM_, DM_);
        dim3 g3(BB / 64, 1);
        gemm_nt<false,false,false,false><<<g3, blk, 0, stream>>>(
            H1B, DM_, a3_W, a3_b, nullptr, nullptr, probs, ADIM_, BB, ADIM_, DM_);
        softmax_kernel<<<BB, 64, 0, stream>>>(probs);
    }
    // 8) critic head
    {
        dim3 g(BB / 64, DM_ / 64);
        gemm_nt<true,false,false,false><<<g, blk, 0, stream>>>(
            COMB, CDIM_, c1_W, c1_b, nullptr, nullptr, H2, DM_, BB, DM_, CDIM_);
        gemm_nt<true,false,false,false><<<g, blk, 0, stream>>>(
            H2, DM_, c2_W, c2_b, nullptr, nullptr, H2B, DM_, BB, DM_, DM_);
        value_kernel<<<BB / 4, 256, 0, stream>>>(H2B, c3_W, c3_b, value);
    }
}

// Round 4
// 3582.972 us; speedup vs baseline: 4.9058x; 4.9058x over previous
//
#include <hip/hip_runtime.h>
#include <math.h>

// ---- problem constants ----
#define BB    2048
#define HIST_ 50
#define ADIM_ 60
#define NL_   3
#define DM_   512
#define DFF_  1024
#define OUT_  256
#define FDIM_ 98
#define KEMB_ 128          // FDIM padded to 128 for MFMA
#define GDIM_ 561
#define CDIM_ 8384
#define MTOK  65536        // B*S
#define NCHUNK 2
#define MC    (MTOK/NCHUNK)  // 32768 rows per chunk
#define BC    (BB/NCHUNK)    // 1024 batch per chunk

typedef unsigned short u16;
typedef unsigned int   u32;
using short8 = __attribute__((ext_vector_type(8))) short;
using f32x4  = __attribute__((ext_vector_type(4))) float;

__device__ __forceinline__ float b2f(u16 h) { return __uint_as_float(((u32)h) << 16); }
__device__ __forceinline__ u16   f2b(float f) {
    u32 u = __float_as_uint(f);
    u32 r = u + 0x7fffu + ((u >> 16) & 1u);   // RNE; inputs finite
    return (u16)(r >> 16);
}
#define GLB(p) ((__attribute__((address_space(1))) void*)(p))
#define LDSP(p) ((__attribute__((address_space(3))) void*)(p))

// =====================================================================
// bf16 MFMA GEMM: C[m,n] = sum_k A[m,k] * W[n,k]  (A,W bf16; f32 accum)
// 128x128 tile, BK=32, 256 threads = 4 waves, each wave 64x64 (4x4 frags
// of 16x16x32). Requires M%128==0, N%128==0, K%32==0.
// MODE bits: 1=RELU 2=RESID 4=ADDPOS 8=PROJSCAT 16=SPLITK(f32 out, no bias)
// =====================================================================
template<int MODE>
__global__ __launch_bounds__(256) void mfma_gemm(
    const u16* __restrict__ A, int lda,
    const u16* __restrict__ W, int ldw,
    const float* __restrict__ bias,
    const u16* __restrict__ resid,
    const float* __restrict__ pos,
    u16* __restrict__ Cb, float* __restrict__ Cf,
    int ldc, int K)
{
    constexpr bool RELU   = (MODE & 1)  != 0;
    constexpr bool RESID  = (MODE & 2)  != 0;
    constexpr bool ADDPOS = (MODE & 4)  != 0;
    constexpr bool PSCAT  = (MODE & 8)  != 0;
    constexpr bool SPLITK = (MODE & 16) != 0;

    __shared__ __align__(16) u16 As[128 * 32];
    __shared__ __align__(16) u16 Bs[128 * 32];
    const int t = threadIdx.x;
    const int l = t & 63, w = t >> 6;
    const int wr = w >> 1, wc = w & 1;
    const int m0 = blockIdx.x * 128, n0 = blockIdx.y * 128;

    f32x4 acc[4][4];
    const f32x4 zero = {0.f, 0.f, 0.f, 0.f};
#pragma unroll
    for (int i = 0; i < 4; ++i)
#pragma unroll
        for (int j = 0; j < 4; ++j) acc[i][j] = zero;

    // staging: chunk c in [0,512): 16B each; row = c>>2, k-offset = (c&3)*8
    const int c0 = t, c1 = t + 256;
    const u16* gA0 = A + (size_t)(m0 + (c0 >> 2)) * lda + (c0 & 3) * 8;
    const u16* gA1 = A + (size_t)(m0 + (c1 >> 2)) * lda + (c1 & 3) * 8;
    const u16* gB0 = W + (size_t)(n0 + (c0 >> 2)) * ldw + (c0 & 3) * 8;
    const u16* gB1 = W + (size_t)(n0 + (c1 >> 2)) * ldw + (c1 & 3) * 8;
    u16* lA0 = &As[c0 * 8]; u16* lA1 = &As[c1 * 8];
    u16* lB0 = &Bs[c0 * 8]; u16* lB1 = &Bs[c1 * 8];

    const int kb = (l >> 4) * 8;
    const int rA = (wr * 64 + (l & 15)) * 32 + kb;
    const int rB = (wc * 64 + (l & 15)) * 32 + kb;

    for (int k0 = 0; k0 < K; k0 += 32) {
        __builtin_amdgcn_global_load_lds(GLB(gA0 + k0), LDSP(lA0), 16, 0, 0);
        __builtin_amdgcn_global_load_lds(GLB(gA1 + k0), LDSP(lA1), 16, 0, 0);
        __builtin_amdgcn_global_load_lds(GLB(gB0 + k0), LDSP(lB0), 16, 0, 0);
        __builtin_amdgcn_global_load_lds(GLB(gB1 + k0), LDSP(lB1), 16, 0, 0);
        __syncthreads();   // compiler drains vmcnt before barrier
        short8 af[4], bfv[4];
#pragma unroll
        for (int mi = 0; mi < 4; ++mi) af[mi]  = *(const short8*)&As[rA + mi * 16 * 32];
#pragma unroll
        for (int ni = 0; ni < 4; ++ni) bfv[ni] = *(const short8*)&Bs[rB + ni * 16 * 32];
#pragma unroll
        for (int mi = 0; mi < 4; ++mi)
#pragma unroll
            for (int ni = 0; ni < 4; ++ni)
                acc[mi][ni] = __builtin_amdgcn_mfma_f32_16x16x32_bf16(
                    af[mi], bfv[ni], acc[mi][ni], 0, 0, 0);
        __syncthreads();
    }

    const int rg = (l >> 4) * 4, cg = l & 15;
#pragma unroll
    for (int mi = 0; mi < 4; ++mi)
#pragma unroll
        for (int ni = 0; ni < 4; ++ni)
#pragma unroll
            for (int r = 0; r < 4; ++r) {
                int m = m0 + wr * 64 + mi * 16 + rg + r;
                int n = n0 + wc * 64 + ni * 16 + cg;
                float v = acc[mi][ni][r];
                if constexpr (SPLITK) { Cf[(size_t)m * ldc + n] = v; continue; }
                v += bias[n];
                if constexpr (ADDPOS) v += pos[(m & 31) * 512 + n];
                size_t oi;
                if constexpr (PSCAT)
                    oi = (size_t)(m >> 5) * CDIM_ + (size_t)(m & 31) * OUT_ + n;
                else
                    oi = (size_t)m * ldc + n;
                if constexpr (RESID) v += b2f(resid[oi]);
                if constexpr (RELU) v = fmaxf(v, 0.f);
                Cb[oi] = f2b(v);
            }
}

// =====================================================================
// small f32 GEMM (bounds-checked): C = A@W^T + bias [, relu]
// A: f32 or bf16; C: f32 or bf16.  64x64 tile, BK=16, 4x4 micro.
// =====================================================================
template<bool RELU, bool ABF16, bool OBF16>
__global__ __launch_bounds__(256) void gemm_small(
    const void* __restrict__ Av, int lda,
    const float* __restrict__ W,
    const float* __restrict__ bias,
    void* __restrict__ Cv, int ldc, int M, int N, int K)
{
    __shared__ __align__(16) float As_[16][68];
    __shared__ __align__(16) float Ws_[16][68];
    const int t  = threadIdx.x;
    const int tx = t & 15, ty = t >> 4;
    const int m0 = blockIdx.x * 64, n0 = blockIdx.y * 64;
    const int kk0  = t & 15;
    const int rowb = t >> 4;
    float acc[4][4] = {};
    for (int k0 = 0; k0 < K; k0 += 16) {
#pragma unroll
        for (int i = 0; i < 4; ++i) {
            int r  = rowb + 16 * i;
            int gk = k0 + kk0;
            int gm = m0 + r;
            float a = 0.f;
            if (gm < M && gk < K)
                a = ABF16 ? b2f(((const u16*)Av)[(size_t)gm * lda + gk])
                          : ((const float*)Av)[(size_t)gm * lda + gk];
            As_[kk0][r] = a;
            int gn = n0 + r;
            Ws_[kk0][r] = (gn < N && gk < K) ? W[(size_t)gn * K + gk] : 0.f;
        }
        __syncthreads();
#pragma unroll
        for (int kk = 0; kk < 16; ++kk) {
            float4 a4 = *(const float4*)(&As_[kk][ty * 4]);
            float4 b4 = *(const float4*)(&Ws_[kk][tx * 4]);
            float av[4] = {a4.x, a4.y, a4.z, a4.w};
            float bv[4] = {b4.x, b4.y, b4.z, b4.w};
#pragma unroll
            for (int i = 0; i < 4; ++i)
#pragma unroll
                for (int j = 0; j < 4; ++j)
                    acc[i][j] = fmaf(av[i], bv[j], acc[i][j]);
        }
        __syncthreads();
    }
#pragma unroll
    for (int i = 0; i < 4; ++i) {
        int m = m0 + ty * 4 + i;
        if (m >= M) continue;
#pragma unroll
        for (int j = 0; j < 4; ++j) {
            int n = n0 + tx * 4 + j;
            if (n >= N) continue;
            float v = acc[i][j] + bias[n];
            if (RELU) v = fmaxf(v, 0.f);
            size_t oi = (size_t)m * ldc + n;
            if (OBF16) ((u16*)Cv)[oi] = f2b(v);
            else       ((float*)Cv)[oi] = v;
        }
    }
}

// =====================================================================
// Features: GS, mu, norms, vf(bf16, padded 128), cos-pairs, f64 LU det, gf(f32)
// =====================================================================
__global__ __launch_bounds__(64) void feat_kernel(
    const float* __restrict__ basis, u16* __restrict__ vfb, float* __restrict__ gf)
{
    const int b = blockIdx.x;
    const int t = threadIdx.x;
    __shared__ float bs[32][33], gsm[32][33], muls[32][32];
    __shared__ float gn2[32], bn_[32], gn_[32];
    __shared__ double lu[32][33];
    __shared__ int piv;
    __shared__ double detv;

    const float* bb = basis + (size_t)b * 1024;
    for (int r = 0; r < 16; ++r) {
        int idx = r * 64 + t;
        bs[idx >> 5][idx & 31] = bb[idx];
    }
    __syncthreads();
    if (t < 32) {
        float s = 0.f;
        for (int d = 0; d < 32; ++d) s = fmaf(bs[t][d], bs[t][d], s);
        bn_[t] = sqrtf(s);
    }
    __syncthreads();

    for (int j = 0; j < 32; ++j) {
        if (t < 32) {
            float m = 0.f;
            if (t < j) {
                float dot = 0.f;
                for (int d = 0; d < 32; ++d) dot = fmaf(gsm[t][d], bs[j][d], dot);
                float sq = gn2[t];
                m = dot / (sq > 0.f ? sq : 1.f);
            }
            muls[j][t] = m;
        }
        __syncthreads();
        float val = 0.f;
        if (t < 32) {
            float acc = bs[j][t];
            for (int k = 0; k < j; ++k) acc = fmaf(-muls[j][k], gsm[k][t], acc);
            gsm[j][t] = acc;
            val = acc * acc;
        }
#pragma unroll
        for (int off = 1; off < 32; off <<= 1) val += __shfl_xor(val, off, 64);
        if (t == 0) { gn2[j] = val; gn_[j] = sqrtf(val); }
        __syncthreads();
    }

    for (int r = 0; r < 16; ++r) {
        int idx = r * 64 + t;
        lu[idx >> 5][idx & 31] = (double)bs[idx >> 5][idx & 31];
    }
    if (t == 0) detv = 1.0;
    __syncthreads();
    for (int k = 0; k < 32; ++k) {
        if (t == 0) {
            int p = k; double best = fabs(lu[k][k]);
            for (int i = k + 1; i < 32; ++i) {
                double a = fabs(lu[i][k]);
                if (a > best) { best = a; p = i; }
            }
            piv = p;
            if (p != k) detv = -detv;
        }
        __syncthreads();
        int p = piv;
        if (p != k && t < 32) {
            double tmp = lu[k][t]; lu[k][t] = lu[p][t]; lu[p][t] = tmp;
        }
        __syncthreads();
        if (t == 0) detv *= lu[k][k];
        double pkk = lu[k][k];
        for (int i = k + 1 + (t >> 5); i < 32; i += 2) {
            double f = (pkk != 0.0) ? (lu[i][k] / pkk) : 0.0;
            int c = t & 31;
            if (c > k) lu[i][c] -= f * lu[k][c];
        }
        __syncthreads();
    }

    // vf bf16 padded to 128 cols
    for (int r = 0; r < 64; ++r) {
        int idx = r * 64 + t;                 // 0..4095
        int i = idx >> 7, c = idx & 127;
        float v = 0.f;
        if (c < 32) v = bs[i][c];
        else if (c < 64) v = gsm[i][c - 32];
        else if (c == 64) v = bn_[i];
        else if (c == 65) v = gn_[i];
        else if (c < 98) v = muls[i][c - 66];
        vfb[(size_t)(b * 32 + i) * KEMB_ + c] = f2b(v);
    }

    float* gfb = gf + (size_t)b * GDIM_;
    for (int r = 0; r < 16; ++r) {
        int p = r * 64 + t;
        int i = p >> 5, j = p & 31;
        if (i < j) {
            float dot = 0.f;
            for (int d = 0; d < 32; ++d) dot = fmaf(bs[i][d], bs[j][d], dot);
            float c = dot / ((bn_[i] + 1e-10f) * (bn_[j] + 1e-10f));
            int L = i * 31 - (i * (i - 1)) / 2 + (j - i - 1);
            gfb[1 + L] = c;
        }
    }
    if (t < 32) {
        gfb[497 + t] = bn_[t];
        gfb[529 + t] = gn_[t];
    }
    if (t == 0) {
        double pb = 1.0;
        for (int i = 0; i < 32; ++i) pb *= (double)bn_[i];
        double det = fabs(detv);
        gfb[0] = (float)(pb / (det + 1e-10));
    }
}

// =====================================================================
// Attention (bf16 in/out, f32 compute); one block per (batch,head);
// O overwrites Q slice in place.
// =====================================================================
__global__ __launch_bounds__(256) void attn_kernel(u16* __restrict__ qkv)
{
    const int b = blockIdx.x >> 2, h = blockIdx.x & 3;
    __shared__ float qs[32][129], ks[32][129], vs_[32][129], ps[32][33];
    u16* base = qkv + (size_t)b * 32 * 1536 + h * 128;
    const int t = threadIdx.x;
    for (int r = 0; r < 16; ++r) {
        int idx = r * 256 + t;
        int s = idx >> 7, d = idx & 127;
        qs[s][d]  = b2f(base[(size_t)s * 1536 + d]);
        ks[s][d]  = b2f(base[(size_t)s * 1536 + 512 + d]);
        vs_[s][d] = b2f(base[(size_t)s * 1536 + 1024 + d]);
    }
    __syncthreads();
    const float scale = 0.08838834764831845f;  // 1/sqrt(128)
#pragma unroll
    for (int r = 0; r < 4; ++r) {
        int p = r * 256 + t;
        int i = p >> 5, j = p & 31;
        float acc = 0.f;
#pragma unroll
        for (int d = 0; d < 128; ++d) acc = fmaf(qs[i][d], ks[j][d], acc);
        ps[i][j] = acc * scale;
    }
    __syncthreads();
    if (t < 32) {
        float mx = -1e30f;
        for (int j = 0; j < 32; ++j) mx = fmaxf(mx, ps[t][j]);
        float sum = 0.f;
        for (int j = 0; j < 32; ++j) { float e = expf(ps[t][j] - mx); ps[t][j] = e; sum += e; }
        float inv = 1.f / sum;
        for (int j = 0; j < 32; ++j) ps[t][j] *= inv;
    }
    __syncthreads();
    for (int r = 0; r < 16; ++r) {
        int idx = r * 256 + t;
        int s = idx >> 7, d = idx & 127;
        float acc = 0.f;
#pragma unroll
        for (int j = 0; j < 32; ++j) acc = fmaf(ps[s][j], vs_[j][d], acc);
        base[(size_t)s * 1536 + d] = f2b(acc);
    }
}

// =====================================================================
// LayerNorm over 512 (bf16 in/out, f32 stats), 4 rows per block
// =====================================================================
__global__ __launch_bounds__(256) void ln_kernel(
    u16* __restrict__ X, const float* __restrict__ g, const float* __restrict__ b)
{
    const int row  = blockIdx.x * 4 + (threadIdx.x >> 6);
    const int lane = threadIdx.x & 63;
    u16* xr = X + (size_t)row * 512;
    uint4 u = *(const uint4*)&xr[lane * 8];
    u32 q[4] = {u.x, u.y, u.z, u.w};
    float v[8];
#pragma unroll
    for (int i = 0; i < 4; ++i) {
        v[2 * i]     = b2f((u16)(q[i] & 0xffffu));
        v[2 * i + 1] = b2f((u16)(q[i] >> 16));
    }
    float s = 0.f;
#pragma unroll
    for (int i = 0; i < 8; ++i) s += v[i];
#pragma unroll
    for (int off = 32; off; off >>= 1) s += __shfl_xor(s, off, 64);
    float mean = s * (1.f / 512.f);
    float vs = 0.f;
#pragma unroll
    for (int i = 0; i < 8; ++i) { float d = v[i] - mean; vs += d * d; }
#pragma unroll
    for (int off = 32; off; off >>= 1) vs += __shfl_xor(vs, off, 64);
    float inv = rsqrtf(vs * (1.f / 512.f) + 1e-5f);
#pragma unroll
    for (int i = 0; i < 4; ++i) {
        int c0 = lane * 8 + 2 * i;
        float o0 = (v[2 * i]     - mean) * inv * g[c0]     + b[c0];
        float o1 = (v[2 * i + 1] - mean) * inv * g[c0 + 1] + b[c0 + 1];
        q[i] = (u32)f2b(o0) | ((u32)f2b(o1) << 16);
    }
    *(uint4*)&xr[lane * 8] = make_uint4(q[0], q[1], q[2], q[3]);
}

// =====================================================================
__global__ __launch_bounds__(256) void gather_kernel(
    const int* __restrict__ hist, const float* __restrict__ act_emb, float* __restrict__ out)
{
    int idx = blockIdx.x * 256 + threadIdx.x;    // B*HIST*32
    if (idx >= BB * HIST_ * 32) return;
    int d = idx & 31, e = idx >> 5;
    int a = hist[e];
    if (a == -1) a = ADIM_;
    out[idx] = act_emb[a * 32 + d];
}

__global__ __launch_bounds__(64) void softmax_kernel(float* __restrict__ logits)
{
    const int row = blockIdx.x;
    const int t = threadIdx.x;
    float v = (t < 60) ? logits[row * 60 + t] : -1e30f;
    float mx = v;
#pragma unroll
    for (int off = 32; off; off >>= 1) mx = fmaxf(mx, __shfl_xor(mx, off, 64));
    float e = (t < 60) ? expf(v - mx) : 0.f;
    float s = e;
#pragma unroll
    for (int off = 32; off; off >>= 1) s += __shfl_xor(s, off, 64);
    if (t < 60) logits[row * 60 + t] = e / s;
}

// value = H34[:,512:1024] @ c3_W + c3_b; 4 rows/block
__global__ __launch_bounds__(256) void value_kernel(
    const u16* __restrict__ H, const float* __restrict__ w,
    const float* __restrict__ bias, float* __restrict__ out)
{
    const int row  = blockIdx.x * 4 + (threadIdx.x >> 6);
    const int lane = threadIdx.x & 63;
    const u16* hr = H + (size_t)row * 1024 + 512 + lane * 8;
    uint4 u = *(const uint4*)hr;
    u32 q[4] = {u.x, u.y, u.z, u.w};
    float s = 0.f;
#pragma unroll
    for (int i = 0; i < 4; ++i) {
        int c = lane * 8 + 2 * i;
        s = fmaf(b2f((u16)(q[i] & 0xffffu)), w[c], s);
        s = fmaf(b2f((u16)(q[i] >> 16)), w[c + 1], s);
    }
#pragma unroll
    for (int off = 32; off; off >>= 1) s += __shfl_xor(s, off, 64);
    if (lane == 0) out[row] = s + bias[0];
}

// split-K reduce for fused heads: out = relu(P0+P1+bias) -> bf16
__global__ __launch_bounds__(256) void reduce2_kernel(
    const float* __restrict__ P, const float* __restrict__ bias, u16* __restrict__ out)
{
    int idx = blockIdx.x * 256 + threadIdx.x;   // 2048*1024
    int n = idx & 1023;
    float v = P[idx] + P[idx + 2048 * 1024] + bias[n];
    out[idx] = f2b(fmaxf(v, 0.f));
}

// ---- weight prep kernels ----
__global__ __launch_bounds__(256) void conv_f2b_kernel(
    const float* __restrict__ s, u16* __restrict__ d, int n)
{
    int i = blockIdx.x * 256 + threadIdx.x;
    if (i < n) d[i] = f2b(s[i]);
}
__global__ __launch_bounds__(256) void pademb_kernel(
    const float* __restrict__ s, u16* __restrict__ d)   // [512][98] -> [512][128]
{
    int i = blockIdx.x * 256 + threadIdx.x;             // 512*128
    if (i >= 512 * KEMB_) return;
    int n = i >> 7, k = i & 127;
    d[i] = f2b(k < FDIM_ ? s[n * FDIM_ + k] : 0.f);
}
__global__ __launch_bounds__(256) void stack2_kernel(
    const float* __restrict__ a, const float* __restrict__ b,
    u16* __restrict__ d, int Kb, int n1rows)            // rows [0,n1):a, rest:b
{
    int i = blockIdx.x * 256 + threadIdx.x;
    int total = 1024 * Kb;
    if (i >= total) return;
    int row = i / Kb;
    d[i] = f2b(row < n1rows ? a[i] : b[i - n1rows * Kb]);
}
__global__ __launch_bounds__(256) void padstackw2_kernel(
    const float* __restrict__ a2, const float* __restrict__ c2, u16* __restrict__ d)
{   // d[1024][1024]: n<512: [a2 | 0] ; n>=512: [0 | c2]
    int i = blockIdx.x * 256 + threadIdx.x;             // 1024*1024
    if (i >= 1024 * 1024) return;
    int n = i >> 10, k = i & 1023;
    float v = 0.f;
    if (n < 512) { if (k < 512) v = a2[n * 512 + k]; }
    else         { if (k >= 512) v = c2[(n - 512) * 512 + (k - 512)]; }
    d[i] = f2b(v);
}
__global__ __launch_bounds__(256) void stackbias_kernel(
    const float* __restrict__ a, const float* __restrict__ b, float* __restrict__ d)
{
    int i = blockIdx.x * 256 + threadIdx.x;             // 1024
    if (i >= 1024) return;
    d[i] = i < 512 ? a[i] : b[i - 512];
}

// =====================================================================
extern "C" void kernel_launch(void* const* d_in, const int* in_sizes, int n_in,
                              void* d_out, int out_size, void* d_ws, size_t ws_size,
                              hipStream_t stream)
{
    const float* basis  = (const float*)d_in[0];
    const int*   hist   = (const int*)  d_in[1];
    const float* emb_W  = (const float*)d_in[2];
    const float* emb_b  = (const float*)d_in[3];
    const float* pos    = (const float*)d_in[4];
    const float* qkv_W  = (const float*)d_in[5];
    const float* qkv_b  = (const float*)d_in[6];
    const float* out_W  = (const float*)d_in[7];
    const float* out_b  = (const float*)d_in[8];
    const float* ln1_g  = (const float*)d_in[9];
    const float* ln1_b  = (const float*)d_in[10];
    const float* ln2_g  = (const float*)d_in[11];
    const float* ln2_b  = (const float*)d_in[12];
    const float* ff1_W  = (const float*)d_in[13];
    const float* ff1_b  = (const float*)d_in[14];
    const float* ff2_W  = (const float*)d_in[15];
    const float* ff2_b  = (const float*)d_in[16];
    const float* proj_W = (const float*)d_in[17];
    const float* proj_b = (const float*)d_in[18];
    const float* g1_W   = (const float*)d_in[19];
    const float* g1_b   = (const float*)d_in[20];
    const float* g2_W   = (const float*)d_in[21];
    const float* g2_b   = (const float*)d_in[22];
    const float* act_emb= (const float*)d_in[23];
    const float* act1_W = (const float*)d_in[24];
    const float* act1_b = (const float*)d_in[25];
    const float* act2_W = (const float*)d_in[26];
    const float* act2_b = (const float*)d_in[27];
    const float* a1_W   = (const float*)d_in[28];
    const float* a1_b   = (const float*)d_in[29];
    const float* a2_W   = (const float*)d_in[30];
    const float* a2_b   = (const float*)d_in[31];
    const float* a3_W   = (const float*)d_in[32];
    const float* a3_b   = (const float*)d_in[33];
    const float* c1_W   = (const float*)d_in[34];
    const float* c1_b   = (const float*)d_in[35];
    const float* c2_W   = (const float*)d_in[36];
    const float* c2_b   = (const float*)d_in[37];
    const float* c3_W   = (const float*)d_in[38];
    const float* c3_b   = (const float*)d_in[39];

    // ---- workspace bump allocation (bytes), ~250 MB ----
    char* p = (char*)d_ws;
    auto nxt = [&](size_t bytes) -> char* {
        char* r = p; p += (bytes + 255) & ~(size_t)255; return r;
    };
    u16*   Xb   = (u16*)  nxt((size_t)MTOK * DM_ * 2);        // 67.1 MB
    u16*   Abuf = (u16*)  nxt((size_t)MC * 1536 * 2);         // 100.7 MB
    u16*   COMB = Abuf;                                       // alias (Abuf dead at proj)
    float* AEIN = (float*)Xb;                                 // alias (Xb dead after proj)
    u16*   VFb  = (u16*)  nxt((size_t)MTOK * KEMB_ * 2);      // 16.8 MB
    float* GF   = (float*)nxt((size_t)BB * GDIM_ * 4);
    float* GE1  = (float*)nxt((size_t)BB * 256 * 4);
    float* AE1  = (float*)nxt((size_t)BB * 128 * 4);
    float* HP   = (float*)nxt((size_t)2 * BB * 1024 * 4);     // 16.8 MB
    u16*   H12  = (u16*)  nxt((size_t)BB * 1024 * 2);
    u16*   H34  = (u16*)  nxt((size_t)BB * 1024 * 2);
    u16*   WQKV = (u16*)  nxt((size_t)3 * 1536 * 512 * 2);
    u16*   WOUT = (u16*)  nxt((size_t)3 * 512 * 512 * 2);
    u16*   WFF1 = (u16*)  nxt((size_t)3 * 1024 * 512 * 2);
    u16*   WFF2 = (u16*)  nxt((size_t)3 * 512 * 1024 * 2);
    u16*   WPROJ= (u16*)  nxt((size_t)256 * 512 * 2);
    u16*   WEMB = (u16*)  nxt((size_t)512 * KEMB_ * 2);
    u16*   WH1  = (u16*)  nxt((size_t)1024 * CDIM_ * 2);      // 17.2 MB
    u16*   WH2  = (u16*)  nxt((size_t)1024 * 1024 * 2);
    float* BH1  = (float*)nxt(4096);
    float* BH2  = (float*)nxt(4096);

    const dim3 blk(256);
    auto cvt = [&](const float* s, u16* d, int n) {
        conv_f2b_kernel<<<(n + 255) / 256, blk, 0, stream>>>(s, d, n);
    };

    // ---- 0) weight prep ----
    cvt(qkv_W, WQKV, 3 * 1536 * 512);
    cvt(out_W, WOUT, 3 * 512 * 512);
    cvt(ff1_W, WFF1, 3 * 1024 * 512);
    cvt(ff2_W, WFF2, 3 * 512 * 1024);
    cvt(proj_W, WPROJ, 256 * 512);
    pademb_kernel<<<(512 * KEMB_ + 255) / 256, blk, 0, stream>>>(emb_W, WEMB);
    stack2_kernel<<<(1024 * CDIM_ + 255) / 256, blk, 0, stream>>>(a1_W, c1_W, WH1, CDIM_, 512);
    padstackw2_kernel<<<(1024 * 1024 + 255) / 256, blk, 0, stream>>>(a2_W, c2_W, WH2);
    stackbias_kernel<<<4, blk, 0, stream>>>(a1_b, c1_b, BH1);
    stackbias_kernel<<<4, blk, 0, stream>>>(a2_b, c2_b, BH2);

    // ---- 1) features ----
    feat_kernel<<<BB, 64, 0, stream>>>(basis, VFb, GF);

    // ---- 2) embed: X = vf @ emb_W.T + b + pos  (K=128 padded) ----
    mfma_gemm<4><<<dim3(MTOK / 128, DM_ / 128), blk, 0, stream>>>(
        VFb, KEMB_, WEMB, KEMB_, emb_b, nullptr, pos, Xb, nullptr, DM_, KEMB_);

    // ---- 3) transformer ----
    for (int l = 0; l < NL_; ++l) {
        const u16* qW = WQKV + (size_t)l * 1536 * 512;
        const u16* oW = WOUT + (size_t)l * 512 * 512;
        const u16* f1W = WFF1 + (size_t)l * 1024 * 512;
        const u16* f2W = WFF2 + (size_t)l * 512 * 1024;
        for (int c = 0; c < NCHUNK; ++c) {
            u16* Xc = Xb + (size_t)c * MC * DM_;
            mfma_gemm<0><<<dim3(MC / 128, 1536 / 128), blk, 0, stream>>>(
                Xc, DM_, qW, DM_, qkv_b + l * 1536, nullptr, nullptr,
                Abuf, nullptr, 1536, DM_);
            attn_kernel<<<BC * 4, blk, 0, stream>>>(Abuf);
            mfma_gemm<2><<<dim3(MC / 128, DM_ / 128), blk, 0, stream>>>(
                Abuf, 1536, oW, DM_, out_b + l * 512, Xc, nullptr,
                Xc, nullptr, DM_, DM_);
        }
        ln_kernel<<<MTOK / 4, blk, 0, stream>>>(Xb, ln1_g + l * 512, ln1_b + l * 512);
        for (int c = 0; c < NCHUNK; ++c) {
            u16* Xc = Xb + (size_t)c * MC * DM_;
            mfma_gemm<1><<<dim3(MC / 128, DFF_ / 128), blk, 0, stream>>>(
                Xc, DM_, f1W, DM_, ff1_b + l * 1024, nullptr, nullptr,
                Abuf, nullptr, DFF_, DM_);
            mfma_gemm<2><<<dim3(MC / 128, DM_ / 128), blk, 0, stream>>>(
                Abuf, DFF_, f2W, DFF_, ff2_b + l * 512, Xc, nullptr,
                Xc, nullptr, DM_, DFF_);
        }
        ln_kernel<<<MTOK / 4, blk, 0, stream>>>(Xb, ln2_g + l * 512, ln2_b + l * 512);
    }

    // ---- 4) proj -> COMB[:, :8192] (bf16 scatter) ----
    mfma_gemm<8><<<dim3(MTOK / 128, OUT_ / 128), blk, 0, stream>>>(
        Xb, DM_, WPROJ, DM_, proj_b, nullptr, nullptr, COMB, nullptr, 0, DM_);

    // ---- 5) global MLP (f32 path; odef magnitudes) -> COMB[:, 8192:8320] ----
    gemm_small<true, false, false><<<dim3(BB / 64, 4), blk, 0, stream>>>(
        GF, GDIM_, g1_W, g1_b, GE1, 256, BB, 256, GDIM_);
    gemm_small<false, false, true><<<dim3(BB / 64, 2), blk, 0, stream>>>(
        GE1, 256, g2_W, g2_b, COMB + 8192, CDIM_, BB, 128, 256);

    // ---- 6) action MLP -> COMB[:, 8320:8384] ----
    gather_kernel<<<(BB * HIST_ * 32 + 255) / 256, blk, 0, stream>>>(hist, act_emb, AEIN);
    gemm_small<true, false, false><<<dim3(BB / 64, 2), blk, 0, stream>>>(
        AEIN, 1600, act1_W, act1_b, AE1, 128, BB, 128, 1600);
    gemm_small<false, false, true><<<dim3(BB / 64, 1), blk, 0, stream>>>(
        AE1, 128, act2_W, act2_b, COMB + 8320, CDIM_, BB, 64, 128);

    // ---- 7) fused heads: [h1|h2] = relu(COMB @ [a1;c1]^T + b), split-K x2 ----
    mfma_gemm<16><<<dim3(BB / 128, 1024 / 128), blk, 0, stream>>>(
        COMB, CDIM_, WH1, CDIM_, nullptr, nullptr, nullptr,
        nullptr, HP, 1024, CDIM_ / 2);
    mfma_gemm<16><<<dim3(BB / 128, 1024 / 128), blk, 0, stream>>>(
        COMB + CDIM_ / 2, CDIM_, WH1 + CDIM_ / 2, CDIM_, nullptr, nullptr, nullptr,
        nullptr, HP + (size_t)BB * 1024, 1024, CDIM_ / 2);
    reduce2_kernel<<<(BB * 1024) / 256, blk, 0, stream>>>(HP, BH1, H12);

    // [h1b|h2b] = relu(H12 @ W2s^T + b2s)  (block-diag stacked)
    mfma_gemm<1><<<dim3(BB / 128, 1024 / 128), blk, 0, stream>>>(
        H12, 1024, WH2, 1024, BH2, nullptr, nullptr, H34, nullptr, 1024, 1024);

    float* probs = (float*)d_out;
    float* value = probs + (size_t)BB * ADIM_;

    gemm_small<false, true, false><<<dim3(BB / 64, 1), blk, 0, stream>>>(
        H34, 1024, a3_W, a3_b, probs, ADIM_, BB, ADIM_, DM_);
    softmax_kernel<<<BB, 64, 0, stream>>>(probs);
    value_kernel<<<BB / 4, blk, 0, stream>>>(H34, c3_W, c3_b, value);
}